// Round 2
// baseline (364.956 us; speedup 1.0000x reference)
//
#include <hip/hip_runtime.h>

// BlockWiseEmbedding: token -> (block b = ba[src], row r = la[src]) -> tableb[r] @ transb -> out[t, 512]
// Input order (setup_inputs dict order, INTERLEAVED):
//   0:src 1:block_assignment 2:local_assignment 3:block0 4:trans0 5:block1 6:trans1
//   7:block2 8:trans2 9:block3 10:trans3
// Fast path: compact tokens by block (packed int list in d_ws), then batched matvec:
// 16 same-block tokens per workgroup, rows staged in LDS, trans elements reused 16x in regs.
// Fallback (ws too small): one workgroup per token, trans served from L2.

#define TOK 16
#define OUT_DIM 512
#define N_TOKENS_MAX 16384

__global__ void scatter_kernel(const int* __restrict__ src,
                               const int* __restrict__ ba,
                               const int* __restrict__ la,
                               int* __restrict__ counts,
                               int* __restrict__ lists,
                               int n_tokens, int stride) {
    int t = blockIdx.x * blockDim.x + threadIdx.x;
    if (t >= n_tokens) return;
    int v = src[t];
    int b = ba[v];
    int r = la[v];
    r = min(max(r, 0), 24999);              // reference clip (no-op here, all tables 25000 rows)
    int pos = atomicAdd(&counts[b], 1);
    lists[b * stride + pos] = t | (r << 14); // t < 2^14, r < 2^15
}

template <int S>
__device__ __forceinline__ void gemm_body(const float* __restrict__ tbl,
                                          const float* __restrict__ tr,
                                          const int* __restrict__ list,
                                          const int* __restrict__ counts,
                                          float* __restrict__ out,
                                          float* lvec, int b) {
    const int n = counts[b];
    const int base = (int)blockIdx.x * TOK;
    if (base >= n) return;
    const int m = min(TOK, n - base);
    const int tid = (int)threadIdx.x;       // 256 threads

    // Stage up to 16 embedding rows (S floats each) into LDS, float4 chunks.
    const int nch = TOK * S / 4;
    for (int i = tid; i < nch; i += 256) {
        const int tok = i / (S / 4);
        const int c   = i % (S / 4);
        float4 v = make_float4(0.f, 0.f, 0.f, 0.f);
        if (tok < m) {
            const int row = list[base + tok] >> 14;
            v = ((const float4*)(tbl + (long)row * S))[c];
        }
        ((float4*)lvec)[i] = v;
    }
    __syncthreads();

    // Each thread owns out dims (tid) and (tid+256) for all 16 tokens.
    float acc0[TOK], acc1[TOK];
#pragma unroll
    for (int tok = 0; tok < TOK; ++tok) { acc0[tok] = 0.f; acc1[tok] = 0.f; }

#pragma unroll 2
    for (int k = 0; k < S; k += 4) {
        float w00 = tr[(k + 0) * OUT_DIM + tid];
        float w01 = tr[(k + 0) * OUT_DIM + tid + 256];
        float w10 = tr[(k + 1) * OUT_DIM + tid];
        float w11 = tr[(k + 1) * OUT_DIM + tid + 256];
        float w20 = tr[(k + 2) * OUT_DIM + tid];
        float w21 = tr[(k + 2) * OUT_DIM + tid + 256];
        float w30 = tr[(k + 3) * OUT_DIM + tid];
        float w31 = tr[(k + 3) * OUT_DIM + tid + 256];
#pragma unroll
        for (int tok = 0; tok < TOK; ++tok) {
            float4 tv = *(const float4*)&lvec[tok * S + k];  // wave-uniform -> broadcast
            acc0[tok] += tv.x * w00 + tv.y * w10 + tv.z * w20 + tv.w * w30;
            acc1[tok] += tv.x * w01 + tv.y * w11 + tv.z * w21 + tv.w * w31;
        }
    }

    for (int tok = 0; tok < m; ++tok) {
        const int t = list[base + tok] & (N_TOKENS_MAX - 1);
        out[(long)t * OUT_DIM + tid]       = acc0[tok];
        out[(long)t * OUT_DIM + tid + 256] = acc1[tok];
    }
}

__global__ __launch_bounds__(256) void gemm_all(
    const float* __restrict__ b0, const float* __restrict__ b1,
    const float* __restrict__ b2, const float* __restrict__ b3,
    const float* __restrict__ t0, const float* __restrict__ t1,
    const float* __restrict__ t2, const float* __restrict__ t3,
    const int* __restrict__ lists, const int* __restrict__ counts,
    float* __restrict__ out, int stride) {
    extern __shared__ float lvec[];         // 16 * 512 * 4B = 32 KiB
    switch ((int)blockIdx.y) {
        case 0: gemm_body<64 >(b0, t0, lists + 0L * stride, counts, out, lvec, 0); break;
        case 1: gemm_body<128>(b1, t1, lists + 1L * stride, counts, out, lvec, 1); break;
        case 2: gemm_body<256>(b2, t2, lists + 2L * stride, counts, out, lvec, 2); break;
        case 3: gemm_body<512>(b3, t3, lists + 3L * stride, counts, out, lvec, 3); break;
    }
}

// ---- Fallback (no workspace): one workgroup per token ----
__global__ __launch_bounds__(256) void per_token_kernel(
    const int* __restrict__ src, const int* __restrict__ ba, const int* __restrict__ la,
    const float* __restrict__ b0, const float* __restrict__ b1,
    const float* __restrict__ b2, const float* __restrict__ b3,
    const float* __restrict__ t0, const float* __restrict__ t1,
    const float* __restrict__ t2, const float* __restrict__ t3,
    float* __restrict__ out) {
    __shared__ float lvec[OUT_DIM];
    const int t = (int)blockIdx.x;
    const int tid = (int)threadIdx.x;
    const int v = src[t];
    const int b = ba[v];
    int r = min(max(la[v], 0), 24999);
    const float* tbl; const float* tr; int S;
    switch (b) {
        case 0: tbl = b0; tr = t0; S = 64;  break;
        case 1: tbl = b1; tr = t1; S = 128; break;
        case 2: tbl = b2; tr = t2; S = 256; break;
        default: tbl = b3; tr = t3; S = 512; break;
    }
    if (tid < S / 4) ((float4*)lvec)[tid] = ((const float4*)(tbl + (long)r * S))[tid];
    __syncthreads();
    float acc0 = 0.f, acc1 = 0.f;
    for (int k = 0; k < S; ++k) {
        float x = lvec[k];
        acc0 += x * tr[k * OUT_DIM + tid];
        acc1 += x * tr[k * OUT_DIM + tid + 256];
    }
    out[(long)t * OUT_DIM + tid]       = acc0;
    out[(long)t * OUT_DIM + tid + 256] = acc1;
}

extern "C" void kernel_launch(void* const* d_in, const int* in_sizes, int n_in,
                              void* d_out, int out_size, void* d_ws, size_t ws_size,
                              hipStream_t stream) {
    const int*   src = (const int*)d_in[0];
    const int*   ba  = (const int*)d_in[1];
    const int*   la  = (const int*)d_in[2];
    const float* b0  = (const float*)d_in[3];
    const float* t0  = (const float*)d_in[4];
    const float* b1  = (const float*)d_in[5];
    const float* t1  = (const float*)d_in[6];
    const float* b2  = (const float*)d_in[7];
    const float* t2  = (const float*)d_in[8];
    const float* b3  = (const float*)d_in[9];
    const float* t3  = (const float*)d_in[10];
    float* out = (float*)d_out;

    const int n_tokens = in_sizes[0];                       // 16384
    const size_t need = 16 + (size_t)4 * n_tokens * sizeof(int);

    if (d_ws != nullptr && ws_size >= need) {
        int* counts = (int*)d_ws;                           // 4 ints (+pad to 16B)
        int* lists  = (int*)((char*)d_ws + 16);             // 4 * n_tokens ints
        hipMemsetAsync(d_ws, 0, 16, stream);
        scatter_kernel<<<(n_tokens + 255) / 256, 256, 0, stream>>>(
            src, ba, la, counts, lists, n_tokens, n_tokens);
        const int groups = (n_tokens + TOK - 1) / TOK;
        dim3 grid(groups, 4);
        gemm_all<<<grid, 256, TOK * OUT_DIM * sizeof(float), stream>>>(
            b0, b1, b2, b3, t0, t1, t2, t3, lists, counts, out, n_tokens);
    } else {
        per_token_kernel<<<n_tokens, 256, 0, stream>>>(
            src, ba, la, b0, b1, b2, b3, t0, t1, t2, t3, out);
    }
}

// Round 3
// 183.143 us; speedup vs baseline: 1.9927x; 1.9927x over previous
//
#include <hip/hip_runtime.h>
#include <stdint.h>

// BlockWiseEmbedding via bf16 MFMA.
// Inputs (setup_inputs dict order, INTERLEAVED):
//   0:src 1:block_assignment 2:local_assignment 3:block0 4:trans0 5:block1 6:trans1
//   7:block2 8:trans2 9:block3 10:trans3
// Pipeline: (1) prep_bsw: trans_b -> bf16 B-fragments pre-swizzled in MFMA lane order (ws);
//           (2) scatter: compact tokens by block (LDS-aggregated atomics);
//           (3) gemm_mfma: per WG 32 same-block tokens x 512 out, A rows staged bf16 in LDS,
//               mfma_f32_16x16x32_bf16, fp32 accumulate, direct store.

#define OUT_DIM 512
#define TOKBITS 14
#define TOKMASK ((1 << TOKBITS) - 1)
#define N_TOKENS_MAX 16384

typedef __attribute__((ext_vector_type(8))) short short8;   // 8 x bf16 (4 VGPRs)
typedef __attribute__((ext_vector_type(4))) float floatx4;  // MFMA C/D

__device__ __forceinline__ uint16_t f2bf(float f) {
    union { float f; uint32_t u; } x; x.f = f;
    uint32_t u = x.u + 0x7FFF + ((x.u >> 16) & 1);  // RNE
    return (uint16_t)(u >> 16);
}

// ---- (1) Pre-swizzle trans matrices into MFMA B-fragment order (bf16) ----
// Frag f of block b: lane=f&63, rest=f>>6, ks=rest%(S/32), ntile=rest/(S/32);
// lane: quad=lane>>4, nl=lane&15 -> B[k=ks*32+quad*8+j][n=ntile*16+nl], j=0..7.
__global__ __launch_bounds__(256) void prep_bsw(
    const float* __restrict__ t0, const float* __restrict__ t1,
    const float* __restrict__ t2, const float* __restrict__ t3,
    uint16_t* __restrict__ bsw) {
    int gid = blockIdx.x * 256 + threadIdx.x;   // 61440 frags total
    const float* tr; int S; int f; uint16_t* dst;
    if (gid < 4096)       { tr = t0; S = 64;  f = gid;         dst = bsw; }
    else if (gid < 12288) { tr = t1; S = 128; f = gid - 4096;  dst = bsw + 64 * 512; }
    else if (gid < 28672) { tr = t2; S = 256; f = gid - 12288; dst = bsw + (64 + 128) * 512; }
    else if (gid < 61440) { tr = t3; S = 512; f = gid - 28672; dst = bsw + (64 + 128 + 256) * 512; }
    else return;
    const int lane = f & 63, rest = f >> 6;
    const int ksteps = S >> 5;
    const int ks = rest & (ksteps - 1), ntile = rest / ksteps;
    const int quad = lane >> 4, nl = lane & 15;
    const int n = ntile * 16 + nl, k0 = ks * 32 + quad * 8;
    short8 v;
#pragma unroll
    for (int j = 0; j < 8; ++j) v[j] = (short)f2bf(tr[(k0 + j) * OUT_DIM + n]);
    *(short8*)(dst + (size_t)f * 8) = v;
}

// ---- (2) Scatter: compact tokens by block, LDS-aggregated counters ----
__global__ __launch_bounds__(256) void scatter_kernel(
    const int* __restrict__ src, const int* __restrict__ ba, const int* __restrict__ la,
    int* __restrict__ counts, int* __restrict__ lists, int n_tokens, int stride) {
    __shared__ int lc[4], gbase[4];
    const int tid = (int)threadIdx.x;
    if (tid < 4) lc[tid] = 0;
    __syncthreads();
    const int t = blockIdx.x * 256 + tid;
    int b = 0, pos = 0, packed = 0;
    const bool active = (t < n_tokens);
    if (active) {
        int v = src[t];
        b = ba[v];
        int r = min(max(la[v], 0), 24999);
        packed = t | (r << TOKBITS);
        pos = atomicAdd(&lc[b], 1);
    }
    __syncthreads();
    if (tid < 4) gbase[tid] = atomicAdd(&counts[tid], lc[tid]);
    __syncthreads();
    if (active) lists[b * stride + gbase[b] + pos] = packed;
}

// ---- (3) MFMA GEMM: 32 tokens x 512 out per WG ----
template <int S>
__device__ __forceinline__ void gemm_mfma_body(
    const float* __restrict__ tbl, const uint16_t* __restrict__ bsw,
    const int* __restrict__ list, const int* __restrict__ counts,
    float* __restrict__ out, uint16_t* lds, int b) {
    const int n = counts[b];
    const int base = (int)blockIdx.x * 32;
    if (base >= n) return;
    const int m = min(32, n - base);
    const int tid = (int)threadIdx.x;
    constexpr int SP = S + 8;              // bf16 row pad: +16B -> uniform bank spread
    constexpr int CH = S / 4;              // float4 chunks per row

    // Stage 32 token rows -> LDS bf16.
    for (int i = tid; i < 32 * CH; i += 256) {
        const int row = i / CH, c = i & (CH - 1);
        float4 v = make_float4(0.f, 0.f, 0.f, 0.f);
        if (row < m) {
            const int r = list[base + row] >> TOKBITS;
            v = ((const float4*)(tbl + (size_t)r * S))[c];
        }
        const uint32_t lo = ((uint32_t)f2bf(v.y) << 16) | f2bf(v.x);
        const uint32_t hi = ((uint32_t)f2bf(v.w) << 16) | f2bf(v.z);
        *(uint2*)(lds + row * SP + c * 4) = make_uint2(lo, hi);
    }
    __syncthreads();

    const int wave = tid >> 6, lane = tid & 63;
    const int quad = lane >> 4, ml = lane & 15;
    constexpr int KS = S / 32;

    floatx4 acc[2][8];
#pragma unroll
    for (int mt = 0; mt < 2; ++mt)
#pragma unroll
        for (int nt = 0; nt < 8; ++nt) acc[mt][nt] = (floatx4)0.f;

    const short8* B = (const short8*)bsw;
#pragma unroll
    for (int ks = 0; ks < KS; ++ks) {
        const short8 a0 = *(const short8*)(lds + ml * SP + ks * 32 + quad * 8);
        const short8 a1 = *(const short8*)(lds + (16 + ml) * SP + ks * 32 + quad * 8);
#pragma unroll
        for (int nt = 0; nt < 8; ++nt) {
            const short8 bf = B[(size_t)((wave * 8 + nt) * KS + ks) * 64 + lane];
            acc[0][nt] = __builtin_amdgcn_mfma_f32_16x16x32_bf16(a0, bf, acc[0][nt], 0, 0, 0);
            acc[1][nt] = __builtin_amdgcn_mfma_f32_16x16x32_bf16(a1, bf, acc[1][nt], 0, 0, 0);
        }
    }

    // C/D: col = lane&15, row = quad*4 + reg.
#pragma unroll
    for (int mt = 0; mt < 2; ++mt) {
#pragma unroll
        for (int r = 0; r < 4; ++r) {
            const int tokidx = mt * 16 + quad * 4 + r;
            if (tokidx < m) {
                const int t = list[base + tokidx] & TOKMASK;
                float* op = out + (size_t)t * OUT_DIM + wave * 128 + ml;
#pragma unroll
                for (int nt = 0; nt < 8; ++nt) op[nt * 16] = acc[mt][nt][r];
            }
        }
    }
}

__global__ __launch_bounds__(256) void gemm_mfma_all(
    const float* __restrict__ b0, const float* __restrict__ b1,
    const float* __restrict__ b2, const float* __restrict__ b3,
    const uint16_t* __restrict__ bsw,
    const int* __restrict__ lists, const int* __restrict__ counts,
    float* __restrict__ out, int stride) {
    extern __shared__ uint16_t lds[];  // 32 * (512+8) * 2 = 33280 B max
    switch ((int)blockIdx.y) {
        case 0: gemm_mfma_body<64 >(b0, bsw,                        lists + 0L * stride, counts, out, lds, 0); break;
        case 1: gemm_mfma_body<128>(b1, bsw + 64 * 512,             lists + 1L * stride, counts, out, lds, 1); break;
        case 2: gemm_mfma_body<256>(b2, bsw + (64 + 128) * 512,     lists + 2L * stride, counts, out, lds, 2); break;
        case 3: gemm_mfma_body<512>(b3, bsw + (64 + 128 + 256) * 512, lists + 3L * stride, counts, out, lds, 3); break;
    }
}

// ---- Fallback fp32 path (ws too small for bsw) ----
#define TOK 16
template <int S>
__device__ __forceinline__ void gemm_body(const float* __restrict__ tbl,
                                          const float* __restrict__ tr,
                                          const int* __restrict__ list,
                                          const int* __restrict__ counts,
                                          float* __restrict__ out,
                                          float* lvec, int b) {
    const int n = counts[b];
    const int base = (int)blockIdx.x * TOK;
    if (base >= n) return;
    const int m = min(TOK, n - base);
    const int tid = (int)threadIdx.x;
    const int nch = TOK * S / 4;
    for (int i = tid; i < nch; i += 256) {
        const int tok = i / (S / 4), c = i % (S / 4);
        float4 v = make_float4(0.f, 0.f, 0.f, 0.f);
        if (tok < m) {
            const int row = list[base + tok] >> TOKBITS;
            v = ((const float4*)(tbl + (size_t)row * S))[c];
        }
        ((float4*)lvec)[i] = v;
    }
    __syncthreads();
    float acc0[TOK], acc1[TOK];
#pragma unroll
    for (int tok = 0; tok < TOK; ++tok) { acc0[tok] = 0.f; acc1[tok] = 0.f; }
#pragma unroll 2
    for (int k = 0; k < S; k += 4) {
        float w00 = tr[(k + 0) * OUT_DIM + tid], w01 = tr[(k + 0) * OUT_DIM + tid + 256];
        float w10 = tr[(k + 1) * OUT_DIM + tid], w11 = tr[(k + 1) * OUT_DIM + tid + 256];
        float w20 = tr[(k + 2) * OUT_DIM + tid], w21 = tr[(k + 2) * OUT_DIM + tid + 256];
        float w30 = tr[(k + 3) * OUT_DIM + tid], w31 = tr[(k + 3) * OUT_DIM + tid + 256];
#pragma unroll
        for (int tok = 0; tok < TOK; ++tok) {
            float4 tv = *(const float4*)&lvec[tok * S + k];
            acc0[tok] += tv.x * w00 + tv.y * w10 + tv.z * w20 + tv.w * w30;
            acc1[tok] += tv.x * w01 + tv.y * w11 + tv.z * w21 + tv.w * w31;
        }
    }
    for (int tok = 0; tok < m; ++tok) {
        const int t = list[base + tok] & TOKMASK;
        out[(size_t)t * OUT_DIM + tid] = acc0[tok];
        out[(size_t)t * OUT_DIM + tid + 256] = acc1[tok];
    }
}

__global__ __launch_bounds__(256) void gemm_all(
    const float* __restrict__ b0, const float* __restrict__ b1,
    const float* __restrict__ b2, const float* __restrict__ b3,
    const float* __restrict__ t0, const float* __restrict__ t1,
    const float* __restrict__ t2, const float* __restrict__ t3,
    const int* __restrict__ lists, const int* __restrict__ counts,
    float* __restrict__ out, int stride) {
    extern __shared__ float lvec[];
    switch ((int)blockIdx.y) {
        case 0: gemm_body<64 >(b0, t0, lists + 0L * stride, counts, out, lvec, 0); break;
        case 1: gemm_body<128>(b1, t1, lists + 1L * stride, counts, out, lvec, 1); break;
        case 2: gemm_body<256>(b2, t2, lists + 2L * stride, counts, out, lvec, 2); break;
        case 3: gemm_body<512>(b3, t3, lists + 3L * stride, counts, out, lvec, 3); break;
    }
}

// ---- Last-resort fallback: one WG per token ----
__global__ __launch_bounds__(256) void per_token_kernel(
    const int* __restrict__ src, const int* __restrict__ ba, const int* __restrict__ la,
    const float* __restrict__ b0, const float* __restrict__ b1,
    const float* __restrict__ b2, const float* __restrict__ b3,
    const float* __restrict__ t0, const float* __restrict__ t1,
    const float* __restrict__ t2, const float* __restrict__ t3,
    float* __restrict__ out) {
    __shared__ float lvec[OUT_DIM];
    const int t = (int)blockIdx.x, tid = (int)threadIdx.x;
    const int v = src[t];
    const int b = ba[v];
    int r = min(max(la[v], 0), 24999);
    const float* tbl; const float* tr; int S;
    switch (b) {
        case 0: tbl = b0; tr = t0; S = 64;  break;
        case 1: tbl = b1; tr = t1; S = 128; break;
        case 2: tbl = b2; tr = t2; S = 256; break;
        default: tbl = b3; tr = t3; S = 512; break;
    }
    if (tid < S / 4) ((float4*)lvec)[tid] = ((const float4*)(tbl + (size_t)r * S))[tid];
    __syncthreads();
    float acc0 = 0.f, acc1 = 0.f;
    for (int k = 0; k < S; ++k) {
        float x = lvec[k];
        acc0 += x * tr[k * OUT_DIM + tid];
        acc1 += x * tr[k * OUT_DIM + tid + 256];
    }
    out[(size_t)t * OUT_DIM + tid] = acc0;
    out[(size_t)t * OUT_DIM + tid + 256] = acc1;
}

extern "C" void kernel_launch(void* const* d_in, const int* in_sizes, int n_in,
                              void* d_out, int out_size, void* d_ws, size_t ws_size,
                              hipStream_t stream) {
    const int*   src = (const int*)d_in[0];
    const int*   ba  = (const int*)d_in[1];
    const int*   la  = (const int*)d_in[2];
    const float* b0  = (const float*)d_in[3];
    const float* t0  = (const float*)d_in[4];
    const float* b1  = (const float*)d_in[5];
    const float* t1  = (const float*)d_in[6];
    const float* b2  = (const float*)d_in[7];
    const float* t2  = (const float*)d_in[8];
    const float* b3  = (const float*)d_in[9];
    const float* t3  = (const float*)d_in[10];
    float* out = (float*)d_out;

    const int n_tokens = in_sizes[0];                   // 16384
    const size_t off_lists = 16;
    const size_t off_bsw   = off_lists + (size_t)4 * n_tokens * sizeof(int);  // 262160
    const size_t bsw_bytes = (size_t)(64 + 128 + 256 + 512) * 512 * sizeof(uint16_t);  // 983040
    const size_t need_full = off_bsw + bsw_bytes;
    const size_t need_fp32 = off_bsw;

    if (d_ws != nullptr && ws_size >= need_full) {
        int* counts   = (int*)d_ws;
        int* lists    = (int*)((char*)d_ws + off_lists);
        uint16_t* bsw = (uint16_t*)((char*)d_ws + off_bsw);
        hipMemsetAsync(d_ws, 0, 16, stream);
        prep_bsw<<<240, 256, 0, stream>>>(t0, t1, t2, t3, bsw);
        scatter_kernel<<<(n_tokens + 255) / 256, 256, 0, stream>>>(
            src, ba, la, counts, lists, n_tokens, n_tokens);
        const int groups = (n_tokens + 31) / 32;
        dim3 grid(groups, 4);
        gemm_mfma_all<<<grid, 256, 32 * (512 + 8) * sizeof(uint16_t), stream>>>(
            b0, b1, b2, b3, bsw, lists, counts, out, n_tokens);
    } else if (d_ws != nullptr && ws_size >= need_fp32) {
        int* counts = (int*)d_ws;
        int* lists  = (int*)((char*)d_ws + off_lists);
        hipMemsetAsync(d_ws, 0, 16, stream);
        scatter_kernel<<<(n_tokens + 255) / 256, 256, 0, stream>>>(
            src, ba, la, counts, lists, n_tokens, n_tokens);
        const int groups = (n_tokens + TOK - 1) / TOK;
        dim3 grid(groups, 4);
        gemm_all<<<grid, 256, TOK * OUT_DIM * sizeof(float), stream>>>(
            b0, b1, b2, b3, t0, t1, t2, t3, lists, counts, out, n_tokens);
    } else {
        per_token_kernel<<<n_tokens, 256, 0, stream>>>(
            src, ba, la, b0, b1, b2, b3, t0, t1, t2, t3, out);
    }
}

// Round 4
// 166.332 us; speedup vs baseline: 2.1941x; 1.1011x over previous
//
#include <hip/hip_runtime.h>
#include <stdint.h>

// BlockWiseEmbedding via bf16 MFMA, v2 (latency fixes).
// Inputs (setup_inputs dict order, INTERLEAVED):
//   0:src 1:block_assignment 2:local_assignment 3:block0 4:trans0 5:block1 6:trans1
//   7:block2 8:trans2 9:block3 10:trans3
// Pipeline: (1) prep_bsw (+zero counts): trans_b -> bf16 MFMA B-fragments in ws;
//           (2) scatter: compact tokens by block (LDS-aggregated atomics);
//           (3) gemm2: flattened indirect grid (no dead WGs), WG = 32 tokens x 256 out dims,
//               acc[2][4] (32 VGPRs) so B-frag loads can stay in flight.

#define OUT_DIM 512
#define TOKBITS 14
#define TOKMASK ((1 << TOKBITS) - 1)

typedef __attribute__((ext_vector_type(8))) short short8;   // 8 x bf16 (4 VGPRs)
typedef __attribute__((ext_vector_type(4))) float floatx4;  // MFMA C/D

__device__ __forceinline__ uint16_t f2bf(float f) {
    union { float f; uint32_t u; } x; x.f = f;
    uint32_t u = x.u + 0x7FFF + ((x.u >> 16) & 1);  // RNE
    return (uint16_t)(u >> 16);
}

// ---- (1) Pre-swizzle trans -> bf16 B-fragments; WG0 also zeroes counts ----
// Frag f within block: lane=f&63, rest=f>>6, ks=rest%KS, ntile=rest/KS;
// lane: quad=lane>>4, nl=lane&15 -> B[k=ks*32+quad*8+j][n=ntile*16+nl], j=0..7.
__global__ __launch_bounds__(256) void prep_bsw(
    const float* __restrict__ t0, const float* __restrict__ t1,
    const float* __restrict__ t2, const float* __restrict__ t3,
    uint16_t* __restrict__ bsw, int* __restrict__ counts) {
    if (blockIdx.x == 0 && threadIdx.x < 4) counts[threadIdx.x] = 0;
    int gid = blockIdx.x * 256 + threadIdx.x;   // 61440 frags total
    const float* tr; int S; int f; uint16_t* dst;
    if (gid < 4096)       { tr = t0; S = 64;  f = gid;         dst = bsw; }
    else if (gid < 12288) { tr = t1; S = 128; f = gid - 4096;  dst = bsw + 64 * 512; }
    else if (gid < 28672) { tr = t2; S = 256; f = gid - 12288; dst = bsw + (64 + 128) * 512; }
    else if (gid < 61440) { tr = t3; S = 512; f = gid - 28672; dst = bsw + (64 + 128 + 256) * 512; }
    else return;
    const int lane = f & 63, rest = f >> 6;
    const int ksteps = S >> 5;
    const int ks = rest & (ksteps - 1), ntile = rest / ksteps;
    const int quad = lane >> 4, nl = lane & 15;
    const int n = ntile * 16 + nl, k0 = ks * 32 + quad * 8;
    short8 v;
#pragma unroll
    for (int j = 0; j < 8; ++j) v[j] = (short)f2bf(tr[(k0 + j) * OUT_DIM + n]);
    *(short8*)(dst + (size_t)f * 8) = v;
}

// ---- (2) Scatter: compact tokens by block, LDS-aggregated counters ----
__global__ __launch_bounds__(256) void scatter_kernel(
    const int* __restrict__ src, const int* __restrict__ ba, const int* __restrict__ la,
    int* __restrict__ counts, int* __restrict__ lists, int n_tokens, int stride) {
    __shared__ int lc[4], gbase[4];
    const int tid = (int)threadIdx.x;
    if (tid < 4) lc[tid] = 0;
    __syncthreads();
    const int t = blockIdx.x * 256 + tid;
    int b = 0, pos = 0, packed = 0;
    const bool active = (t < n_tokens);
    if (active) {
        int v = src[t];
        b = ba[v];
        int r = min(max(la[v], 0), 24999);
        packed = t | (r << TOKBITS);
        pos = atomicAdd(&lc[b], 1);
    }
    __syncthreads();
    if (tid < 4) gbase[tid] = atomicAdd(&counts[tid], lc[tid]);
    __syncthreads();
    if (active) lists[b * stride + gbase[b] + pos] = packed;
}

// ---- (3) MFMA GEMM v2: 32 tokens x 256 out dims per WG, indirect flattened grid ----
template <int S>
__device__ __forceinline__ void gemm2_body(
    const float* __restrict__ tbl, const uint16_t* __restrict__ bswb,
    const int* __restrict__ list, int n, int g, int nhalf,
    float* __restrict__ out, uint16_t* lds) {
    const int base = g * 32;
    const int m = min(32, n - base);
    const int tid = (int)threadIdx.x;
    constexpr int SP = S + 24;             // row stride ≡ 48 mod 128 B -> best bank spread
    constexpr int CH = S / 4;              // float4 chunks per row
    constexpr int KS = S / 32;

    // Stage 32 token rows -> LDS bf16.
    for (int i = tid; i < 32 * CH; i += 256) {
        const int row = i / CH, c = i & (CH - 1);
        float4 v = make_float4(0.f, 0.f, 0.f, 0.f);
        if (row < m) {
            const int r = list[base + row] >> TOKBITS;
            v = ((const float4*)(tbl + (size_t)r * S))[c];
        }
        const uint32_t lo = ((uint32_t)f2bf(v.y) << 16) | f2bf(v.x);
        const uint32_t hi = ((uint32_t)f2bf(v.w) << 16) | f2bf(v.z);
        *(uint2*)(lds + row * SP + c * 4) = make_uint2(lo, hi);
    }
    __syncthreads();

    const int wave = tid >> 6, lane = tid & 63;
    const int quad = lane >> 4, ml = lane & 15;
    const int ntb = nhalf * 16 + wave * 4;  // this wave's first of 4 ntiles

    floatx4 acc[2][4];
#pragma unroll
    for (int mt = 0; mt < 2; ++mt)
#pragma unroll
        for (int nt = 0; nt < 4; ++nt) acc[mt][nt] = (floatx4)0.f;

    const short8* B = (const short8*)bswb;
#pragma unroll
    for (int ks = 0; ks < KS; ++ks) {
        const short8 a0 = *(const short8*)(lds + ml * SP + ks * 32 + quad * 8);
        const short8 a1 = *(const short8*)(lds + (16 + ml) * SP + ks * 32 + quad * 8);
#pragma unroll
        for (int nt = 0; nt < 4; ++nt) {
            const short8 bf = B[(size_t)((ntb + nt) * KS + ks) * 64 + lane];
            acc[0][nt] = __builtin_amdgcn_mfma_f32_16x16x32_bf16(a0, bf, acc[0][nt], 0, 0, 0);
            acc[1][nt] = __builtin_amdgcn_mfma_f32_16x16x32_bf16(a1, bf, acc[1][nt], 0, 0, 0);
        }
    }

    // C/D: col = lane&15, row = quad*4 + reg.
#pragma unroll
    for (int mt = 0; mt < 2; ++mt) {
#pragma unroll
        for (int r = 0; r < 4; ++r) {
            const int tokidx = mt * 16 + quad * 4 + r;
            if (tokidx < m) {
                const int t = list[base + tokidx] & TOKMASK;
                float* op = out + (size_t)t * OUT_DIM + nhalf * 256 + wave * 64 + ml;
#pragma unroll
                for (int nt = 0; nt < 4; ++nt) op[nt * 16] = acc[mt][nt][r];
            }
        }
    }
}

__global__ __launch_bounds__(256, 4) void gemm_mfma_v2(
    const float* __restrict__ b0, const float* __restrict__ b1,
    const float* __restrict__ b2, const float* __restrict__ b3,
    const uint16_t* __restrict__ bsw,
    const int* __restrict__ lists, const int* __restrict__ counts,
    float* __restrict__ out, int stride) {
    extern __shared__ uint16_t lds[];       // 32 * (512+24) * 2 = 34304 B
    const int c0 = counts[0], c1 = counts[1], c2 = counts[2], c3 = counts[3];
    const int g0 = (c0 + 31) >> 5, g1 = (c1 + 31) >> 5, g2 = (c2 + 31) >> 5, g3 = (c3 + 31) >> 5;
    const int flat = (int)blockIdx.x;
    const int nhalf = (int)blockIdx.y;
    if (flat >= g0 + g1 + g2 + g3) return;
    if (flat < g0) {
        gemm2_body<64 >(b0, bsw, lists + 0L * stride, c0, flat, nhalf, out, lds);
    } else if (flat < g0 + g1) {
        gemm2_body<128>(b1, bsw + 64 * 512, lists + 1L * stride, c1, flat - g0, nhalf, out, lds);
    } else if (flat < g0 + g1 + g2) {
        gemm2_body<256>(b2, bsw + (64 + 128) * 512, lists + 2L * stride, c2, flat - g0 - g1, nhalf, out, lds);
    } else {
        gemm2_body<512>(b3, bsw + (64 + 128 + 256) * 512, lists + 3L * stride, c3, flat - g0 - g1 - g2, nhalf, out, lds);
    }
}

// ---- Fallback fp32 path (ws too small for bsw) ----
#define TOK 16
template <int S>
__device__ __forceinline__ void gemm_body(const float* __restrict__ tbl,
                                          const float* __restrict__ tr,
                                          const int* __restrict__ list,
                                          const int* __restrict__ counts,
                                          float* __restrict__ out,
                                          float* lvec, int b) {
    const int n = counts[b];
    const int base = (int)blockIdx.x * TOK;
    if (base >= n) return;
    const int m = min(TOK, n - base);
    const int tid = (int)threadIdx.x;
    const int nch = TOK * S / 4;
    for (int i = tid; i < nch; i += 256) {
        const int tok = i / (S / 4), c = i % (S / 4);
        float4 v = make_float4(0.f, 0.f, 0.f, 0.f);
        if (tok < m) {
            const int row = list[base + tok] >> TOKBITS;
            v = ((const float4*)(tbl + (size_t)row * S))[c];
        }
        ((float4*)lvec)[i] = v;
    }
    __syncthreads();
    float acc0[TOK], acc1[TOK];
#pragma unroll
    for (int tok = 0; tok < TOK; ++tok) { acc0[tok] = 0.f; acc1[tok] = 0.f; }
#pragma unroll 2
    for (int k = 0; k < S; k += 4) {
        float w00 = tr[(k + 0) * OUT_DIM + tid], w01 = tr[(k + 0) * OUT_DIM + tid + 256];
        float w10 = tr[(k + 1) * OUT_DIM + tid], w11 = tr[(k + 1) * OUT_DIM + tid + 256];
        float w20 = tr[(k + 2) * OUT_DIM + tid], w21 = tr[(k + 2) * OUT_DIM + tid + 256];
        float w30 = tr[(k + 3) * OUT_DIM + tid], w31 = tr[(k + 3) * OUT_DIM + tid + 256];
#pragma unroll
        for (int tok = 0; tok < TOK; ++tok) {
            float4 tv = *(const float4*)&lvec[tok * S + k];
            acc0[tok] += tv.x * w00 + tv.y * w10 + tv.z * w20 + tv.w * w30;
            acc1[tok] += tv.x * w01 + tv.y * w11 + tv.z * w21 + tv.w * w31;
        }
    }
    for (int tok = 0; tok < m; ++tok) {
        const int t = list[base + tok] & TOKMASK;
        out[(size_t)t * OUT_DIM + tid] = acc0[tok];
        out[(size_t)t * OUT_DIM + tid + 256] = acc1[tok];
    }
}

__global__ __launch_bounds__(256) void gemm_all(
    const float* __restrict__ b0, const float* __restrict__ b1,
    const float* __restrict__ b2, const float* __restrict__ b3,
    const float* __restrict__ t0, const float* __restrict__ t1,
    const float* __restrict__ t2, const float* __restrict__ t3,
    const int* __restrict__ lists, const int* __restrict__ counts,
    float* __restrict__ out, int stride) {
    extern __shared__ float lvec[];
    switch ((int)blockIdx.y) {
        case 0: gemm_body<64 >(b0, t0, lists + 0L * stride, counts, out, lvec, 0); break;
        case 1: gemm_body<128>(b1, t1, lists + 1L * stride, counts, out, lvec, 1); break;
        case 2: gemm_body<256>(b2, t2, lists + 2L * stride, counts, out, lvec, 2); break;
        case 3: gemm_body<512>(b3, t3, lists + 3L * stride, counts, out, lvec, 3); break;
    }
}

// ---- Last-resort fallback: one WG per token ----
__global__ __launch_bounds__(256) void per_token_kernel(
    const int* __restrict__ src, const int* __restrict__ ba, const int* __restrict__ la,
    const float* __restrict__ b0, const float* __restrict__ b1,
    const float* __restrict__ b2, const float* __restrict__ b3,
    const float* __restrict__ t0, const float* __restrict__ t1,
    const float* __restrict__ t2, const float* __restrict__ t3,
    float* __restrict__ out) {
    __shared__ float lvec[OUT_DIM];
    const int t = (int)blockIdx.x, tid = (int)threadIdx.x;
    const int v = src[t];
    const int b = ba[v];
    int r = min(max(la[v], 0), 24999);
    const float* tbl; const float* tr; int S;
    switch (b) {
        case 0: tbl = b0; tr = t0; S = 64;  break;
        case 1: tbl = b1; tr = t1; S = 128; break;
        case 2: tbl = b2; tr = t2; S = 256; break;
        default: tbl = b3; tr = t3; S = 512; break;
    }
    if (tid < S / 4) ((float4*)lvec)[tid] = ((const float4*)(tbl + (size_t)r * S))[tid];
    __syncthreads();
    float acc0 = 0.f, acc1 = 0.f;
    for (int k = 0; k < S; ++k) {
        float x = lvec[k];
        acc0 += x * tr[k * OUT_DIM + tid];
        acc1 += x * tr[k * OUT_DIM + tid + 256];
    }
    out[(size_t)t * OUT_DIM + tid] = acc0;
    out[(size_t)t * OUT_DIM + tid + 256] = acc1;
}

extern "C" void kernel_launch(void* const* d_in, const int* in_sizes, int n_in,
                              void* d_out, int out_size, void* d_ws, size_t ws_size,
                              hipStream_t stream) {
    const int*   src = (const int*)d_in[0];
    const int*   ba  = (const int*)d_in[1];
    const int*   la  = (const int*)d_in[2];
    const float* b0  = (const float*)d_in[3];
    const float* t0  = (const float*)d_in[4];
    const float* b1  = (const float*)d_in[5];
    const float* t1  = (const float*)d_in[6];
    const float* b2  = (const float*)d_in[7];
    const float* t2  = (const float*)d_in[8];
    const float* b3  = (const float*)d_in[9];
    const float* t3  = (const float*)d_in[10];
    float* out = (float*)d_out;

    const int n_tokens = in_sizes[0];                   // 16384
    const size_t off_lists = 16;
    const size_t off_bsw   = off_lists + (size_t)4 * n_tokens * sizeof(int);
    const size_t bsw_bytes = (size_t)(64 + 128 + 256 + 512) * 512 * sizeof(uint16_t);
    const size_t need_full = off_bsw + bsw_bytes;
    const size_t need_fp32 = off_bsw;

    if (d_ws != nullptr && ws_size >= need_full) {
        int* counts   = (int*)d_ws;
        int* lists    = (int*)((char*)d_ws + off_lists);
        uint16_t* bsw = (uint16_t*)((char*)d_ws + off_bsw);
        prep_bsw<<<240, 256, 0, stream>>>(t0, t1, t2, t3, bsw, counts);
        scatter_kernel<<<(n_tokens + 255) / 256, 256, 0, stream>>>(
            src, ba, la, counts, lists, n_tokens, n_tokens);
        const int gmax = (n_tokens + 31) / 32 + 3;      // worst-case flattened groups
        dim3 grid(gmax, 2);
        gemm_mfma_v2<<<grid, 256, 32 * (512 + 24) * sizeof(uint16_t), stream>>>(
            b0, b1, b2, b3, bsw, lists, counts, out, n_tokens);
    } else if (d_ws != nullptr && ws_size >= need_fp32) {
        int* counts = (int*)d_ws;
        int* lists  = (int*)((char*)d_ws + off_lists);
        hipMemsetAsync(d_ws, 0, 16, stream);
        scatter_kernel<<<(n_tokens + 255) / 256, 256, 0, stream>>>(
            src, ba, la, counts, lists, n_tokens, n_tokens);
        const int groups = (n_tokens + TOK - 1) / TOK;
        dim3 grid(groups, 4);
        gemm_all<<<grid, 256, TOK * OUT_DIM * sizeof(float), stream>>>(
            b0, b1, b2, b3, t0, t1, t2, t3, lists, counts, out, n_tokens);
    } else {
        per_token_kernel<<<n_tokens, 256, 0, stream>>>(
            src, ba, la, b0, b1, b2, b3, t0, t1, t2, t3, out);
    }
}

// Round 5
// 156.453 us; speedup vs baseline: 2.3327x; 1.0631x over previous
//
#include <hip/hip_runtime.h>
#include <stdint.h>

// BlockWiseEmbedding via bf16 MFMA, v3 (TLP: 16-token tiles, 24 waves/CU).
// Inputs (setup_inputs dict order, INTERLEAVED):
//   0:src 1:block_assignment 2:local_assignment 3:block0 4:trans0 5:block1 6:trans1
//   7:block2 8:trans2 9:block3 10:trans3
// Pipeline: (1) prep_bsw (+zero counts): trans_b -> bf16 MFMA B-fragments in ws;
//           (2) scatter: compact tokens by block (LDS-aggregated atomics);
//           (3) gemm3: flattened indirect grid, WG = 16 tokens x 256 out dims, acc[4]
//               (16 VGPRs) -> high occupancy to hide L2 latency on B-fragment loads.

#define OUT_DIM 512
#define TOKBITS 14
#define TOKMASK ((1 << TOKBITS) - 1)

typedef __attribute__((ext_vector_type(8))) short short8;   // 8 x bf16 (4 VGPRs)
typedef __attribute__((ext_vector_type(4))) float floatx4;  // MFMA C/D

__device__ __forceinline__ uint16_t f2bf(float f) {
    union { float f; uint32_t u; } x; x.f = f;
    uint32_t u = x.u + 0x7FFF + ((x.u >> 16) & 1);  // RNE
    return (uint16_t)(u >> 16);
}

// ---- (1) Pre-swizzle trans -> bf16 B-fragments; WG0 also zeroes counts ----
// Frag f within block: lane=f&63, rest=f>>6, ks=rest%KS, ntile=rest/KS;
// lane: quad=lane>>4, nl=lane&15 -> B[k=ks*32+quad*8+j][n=ntile*16+nl], j=0..7.
__global__ __launch_bounds__(256) void prep_bsw(
    const float* __restrict__ t0, const float* __restrict__ t1,
    const float* __restrict__ t2, const float* __restrict__ t3,
    uint16_t* __restrict__ bsw, int* __restrict__ counts) {
    if (blockIdx.x == 0 && threadIdx.x < 4) counts[threadIdx.x] = 0;
    int gid = blockIdx.x * 256 + threadIdx.x;   // 61440 frags total
    const float* tr; int S; int f; uint16_t* dst;
    if (gid < 4096)       { tr = t0; S = 64;  f = gid;         dst = bsw; }
    else if (gid < 12288) { tr = t1; S = 128; f = gid - 4096;  dst = bsw + 64 * 512; }
    else if (gid < 28672) { tr = t2; S = 256; f = gid - 12288; dst = bsw + (64 + 128) * 512; }
    else if (gid < 61440) { tr = t3; S = 512; f = gid - 28672; dst = bsw + (64 + 128 + 256) * 512; }
    else return;
    const int lane = f & 63, rest = f >> 6;
    const int ksteps = S >> 5;
    const int ks = rest & (ksteps - 1), ntile = rest / ksteps;
    const int quad = lane >> 4, nl = lane & 15;
    const int n = ntile * 16 + nl, k0 = ks * 32 + quad * 8;
    short8 v;
#pragma unroll
    for (int j = 0; j < 8; ++j) v[j] = (short)f2bf(tr[(k0 + j) * OUT_DIM + n]);
    *(short8*)(dst + (size_t)f * 8) = v;
}

// ---- (2) Scatter: compact tokens by block, LDS-aggregated counters ----
__global__ __launch_bounds__(256) void scatter_kernel(
    const int* __restrict__ src, const int* __restrict__ ba, const int* __restrict__ la,
    int* __restrict__ counts, int* __restrict__ lists, int n_tokens, int stride) {
    __shared__ int lc[4], gbase[4];
    const int tid = (int)threadIdx.x;
    if (tid < 4) lc[tid] = 0;
    __syncthreads();
    const int t = blockIdx.x * 256 + tid;
    int b = 0, pos = 0, packed = 0;
    const bool active = (t < n_tokens);
    if (active) {
        int v = src[t];
        b = ba[v];
        int r = min(max(la[v], 0), 24999);
        packed = t | (r << TOKBITS);
        pos = atomicAdd(&lc[b], 1);
    }
    __syncthreads();
    if (tid < 4) gbase[tid] = atomicAdd(&counts[tid], lc[tid]);
    __syncthreads();
    if (active) lists[b * stride + gbase[b] + pos] = packed;
}

// ---- (3) MFMA GEMM v3: 16 tokens x 256 out dims per WG, indirect flattened grid ----
template <int S>
__device__ __forceinline__ void gemm3_body(
    const float* __restrict__ tbl, const uint16_t* __restrict__ bswb,
    const int* __restrict__ list, int n, int g, int nhalf,
    float* __restrict__ out, uint16_t* lds) {
    const int base = g * 16;
    const int m = min(16, n - base);
    const int tid = (int)threadIdx.x;
    constexpr int SP = S + 8;              // 16B-group stride odd -> 2-way max (free)
    constexpr int CH = S / 4;              // float4 chunks per row
    constexpr int KS = S / 32;

    // Stage 16 token rows -> LDS bf16.
    for (int i = tid; i < 16 * CH; i += 256) {
        const int row = i / CH, c = i & (CH - 1);
        float4 v = make_float4(0.f, 0.f, 0.f, 0.f);
        if (row < m) {
            const int r = list[base + row] >> TOKBITS;
            v = ((const float4*)(tbl + (size_t)r * S))[c];
        }
        const uint32_t lo = ((uint32_t)f2bf(v.y) << 16) | f2bf(v.x);
        const uint32_t hi = ((uint32_t)f2bf(v.w) << 16) | f2bf(v.z);
        *(uint2*)(lds + row * SP + c * 4) = make_uint2(lo, hi);
    }
    __syncthreads();

    const int wave = tid >> 6, lane = tid & 63;
    const int quad = lane >> 4, ml = lane & 15;
    const int ntb = nhalf * 16 + wave * 4;  // this wave's first of 4 ntiles

    floatx4 acc[4];
#pragma unroll
    for (int nt = 0; nt < 4; ++nt) acc[nt] = (floatx4)0.f;

    const short8* B = (const short8*)bswb;
#pragma unroll
    for (int ks = 0; ks < KS; ++ks) {
        const short8 a = *(const short8*)(lds + ml * SP + ks * 32 + quad * 8);
#pragma unroll
        for (int nt = 0; nt < 4; ++nt) {
            const short8 bf = B[(size_t)((ntb + nt) * KS + ks) * 64 + lane];
            acc[nt] = __builtin_amdgcn_mfma_f32_16x16x32_bf16(a, bf, acc[nt], 0, 0, 0);
        }
    }

    // C/D: col = lane&15, row = quad*4 + reg.
#pragma unroll
    for (int r = 0; r < 4; ++r) {
        const int tokidx = quad * 4 + r;
        if (tokidx < m) {
            const int t = list[base + tokidx] & TOKMASK;
            float* op = out + (size_t)t * OUT_DIM + nhalf * 256 + wave * 64 + ml;
#pragma unroll
            for (int nt = 0; nt < 4; ++nt) op[nt * 16] = acc[nt][r];
        }
    }
}

__global__ __launch_bounds__(256, 6) void gemm_mfma_v3(
    const float* __restrict__ b0, const float* __restrict__ b1,
    const float* __restrict__ b2, const float* __restrict__ b3,
    const uint16_t* __restrict__ bsw,
    const int* __restrict__ lists, const int* __restrict__ counts,
    float* __restrict__ out, int stride) {
    extern __shared__ uint16_t lds[];       // 16 * (512+8) * 2 = 16640 B max
    const int c0 = counts[0], c1 = counts[1], c2 = counts[2], c3 = counts[3];
    const int g0 = (c0 + 15) >> 4, g1 = (c1 + 15) >> 4, g2 = (c2 + 15) >> 4, g3 = (c3 + 15) >> 4;
    const int flat = (int)blockIdx.x;
    const int nhalf = (int)blockIdx.y;
    if (flat >= g0 + g1 + g2 + g3) return;
    if (flat < g0) {
        gemm3_body<64 >(b0, bsw, lists + 0L * stride, c0, flat, nhalf, out, lds);
    } else if (flat < g0 + g1) {
        gemm3_body<128>(b1, bsw + 64 * 512, lists + 1L * stride, c1, flat - g0, nhalf, out, lds);
    } else if (flat < g0 + g1 + g2) {
        gemm3_body<256>(b2, bsw + (64 + 128) * 512, lists + 2L * stride, c2, flat - g0 - g1, nhalf, out, lds);
    } else {
        gemm3_body<512>(b3, bsw + (64 + 128 + 256) * 512, lists + 3L * stride, c3, flat - g0 - g1 - g2, nhalf, out, lds);
    }
}

// ---- Fallback fp32 path (ws too small for bsw) ----
#define TOK 16
template <int S>
__device__ __forceinline__ void gemm_body(const float* __restrict__ tbl,
                                          const float* __restrict__ tr,
                                          const int* __restrict__ list,
                                          const int* __restrict__ counts,
                                          float* __restrict__ out,
                                          float* lvec, int b) {
    const int n = counts[b];
    const int base = (int)blockIdx.x * TOK;
    if (base >= n) return;
    const int m = min(TOK, n - base);
    const int tid = (int)threadIdx.x;
    const int nch = TOK * S / 4;
    for (int i = tid; i < nch; i += 256) {
        const int tok = i / (S / 4), c = i % (S / 4);
        float4 v = make_float4(0.f, 0.f, 0.f, 0.f);
        if (tok < m) {
            const int row = list[base + tok] >> TOKBITS;
            v = ((const float4*)(tbl + (size_t)row * S))[c];
        }
        ((float4*)lvec)[i] = v;
    }
    __syncthreads();
    float acc0[TOK], acc1[TOK];
#pragma unroll
    for (int tok = 0; tok < TOK; ++tok) { acc0[tok] = 0.f; acc1[tok] = 0.f; }
#pragma unroll 2
    for (int k = 0; k < S; k += 4) {
        float w00 = tr[(k + 0) * OUT_DIM + tid], w01 = tr[(k + 0) * OUT_DIM + tid + 256];
        float w10 = tr[(k + 1) * OUT_DIM + tid], w11 = tr[(k + 1) * OUT_DIM + tid + 256];
        float w20 = tr[(k + 2) * OUT_DIM + tid], w21 = tr[(k + 2) * OUT_DIM + tid + 256];
        float w30 = tr[(k + 3) * OUT_DIM + tid], w31 = tr[(k + 3) * OUT_DIM + tid + 256];
#pragma unroll
        for (int tok = 0; tok < TOK; ++tok) {
            float4 tv = *(const float4*)&lvec[tok * S + k];
            acc0[tok] += tv.x * w00 + tv.y * w10 + tv.z * w20 + tv.w * w30;
            acc1[tok] += tv.x * w01 + tv.y * w11 + tv.z * w21 + tv.w * w31;
        }
    }
    for (int tok = 0; tok < m; ++tok) {
        const int t = list[base + tok] & TOKMASK;
        out[(size_t)t * OUT_DIM + tid] = acc0[tok];
        out[(size_t)t * OUT_DIM + tid + 256] = acc1[tok];
    }
}

__global__ __launch_bounds__(256) void gemm_all(
    const float* __restrict__ b0, const float* __restrict__ b1,
    const float* __restrict__ b2, const float* __restrict__ b3,
    const float* __restrict__ t0, const float* __restrict__ t1,
    const float* __restrict__ t2, const float* __restrict__ t3,
    const int* __restrict__ lists, const int* __restrict__ counts,
    float* __restrict__ out, int stride) {
    extern __shared__ float lvec[];
    switch ((int)blockIdx.y) {
        case 0: gemm_body<64 >(b0, t0, lists + 0L * stride, counts, out, lvec, 0); break;
        case 1: gemm_body<128>(b1, t1, lists + 1L * stride, counts, out, lvec, 1); break;
        case 2: gemm_body<256>(b2, t2, lists + 2L * stride, counts, out, lvec, 2); break;
        case 3: gemm_body<512>(b3, t3, lists + 3L * stride, counts, out, lvec, 3); break;
    }
}

// ---- Last-resort fallback: one WG per token ----
__global__ __launch_bounds__(256) void per_token_kernel(
    const int* __restrict__ src, const int* __restrict__ ba, const int* __restrict__ la,
    const float* __restrict__ b0, const float* __restrict__ b1,
    const float* __restrict__ b2, const float* __restrict__ b3,
    const float* __restrict__ t0, const float* __restrict__ t1,
    const float* __restrict__ t2, const float* __restrict__ t3,
    float* __restrict__ out) {
    __shared__ float lvec[OUT_DIM];
    const int t = (int)blockIdx.x, tid = (int)threadIdx.x;
    const int v = src[t];
    const int b = ba[v];
    int r = min(max(la[v], 0), 24999);
    const float* tbl; const float* tr; int S;
    switch (b) {
        case 0: tbl = b0; tr = t0; S = 64;  break;
        case 1: tbl = b1; tr = t1; S = 128; break;
        case 2: tbl = b2; tr = t2; S = 256; break;
        default: tbl = b3; tr = t3; S = 512; break;
    }
    if (tid < S / 4) ((float4*)lvec)[tid] = ((const float4*)(tbl + (size_t)r * S))[tid];
    __syncthreads();
    float acc0 = 0.f, acc1 = 0.f;
    for (int k = 0; k < S; ++k) {
        float x = lvec[k];
        acc0 += x * tr[k * OUT_DIM + tid];
        acc1 += x * tr[k * OUT_DIM + tid + 256];
    }
    out[(size_t)t * OUT_DIM + tid] = acc0;
    out[(size_t)t * OUT_DIM + tid + 256] = acc1;
}

extern "C" void kernel_launch(void* const* d_in, const int* in_sizes, int n_in,
                              void* d_out, int out_size, void* d_ws, size_t ws_size,
                              hipStream_t stream) {
    const int*   src = (const int*)d_in[0];
    const int*   ba  = (const int*)d_in[1];
    const int*   la  = (const int*)d_in[2];
    const float* b0  = (const float*)d_in[3];
    const float* t0  = (const float*)d_in[4];
    const float* b1  = (const float*)d_in[5];
    const float* t1  = (const float*)d_in[6];
    const float* b2  = (const float*)d_in[7];
    const float* t2  = (const float*)d_in[8];
    const float* b3  = (const float*)d_in[9];
    const float* t3  = (const float*)d_in[10];
    float* out = (float*)d_out;

    const int n_tokens = in_sizes[0];                   // 16384
    const size_t off_lists = 16;
    const size_t off_bsw   = off_lists + (size_t)4 * n_tokens * sizeof(int);
    const size_t bsw_bytes = (size_t)(64 + 128 + 256 + 512) * 512 * sizeof(uint16_t);
    const size_t need_full = off_bsw + bsw_bytes;
    const size_t need_fp32 = off_bsw;

    if (d_ws != nullptr && ws_size >= need_full) {
        int* counts   = (int*)d_ws;
        int* lists    = (int*)((char*)d_ws + off_lists);
        uint16_t* bsw = (uint16_t*)((char*)d_ws + off_bsw);
        prep_bsw<<<240, 256, 0, stream>>>(t0, t1, t2, t3, bsw, counts);
        scatter_kernel<<<(n_tokens + 255) / 256, 256, 0, stream>>>(
            src, ba, la, counts, lists, n_tokens, n_tokens);
        const int gmax = (n_tokens + 15) / 16 + 3;      // worst-case flattened groups
        dim3 grid(gmax, 2);
        gemm_mfma_v3<<<grid, 256, 16 * (512 + 8) * sizeof(uint16_t), stream>>>(
            b0, b1, b2, b3, bsw, lists, counts, out, n_tokens);
    } else if (d_ws != nullptr && ws_size >= need_fp32) {
        int* counts = (int*)d_ws;
        int* lists  = (int*)((char*)d_ws + off_lists);
        hipMemsetAsync(d_ws, 0, 16, stream);
        scatter_kernel<<<(n_tokens + 255) / 256, 256, 0, stream>>>(
            src, ba, la, counts, lists, n_tokens, n_tokens);
        const int groups = (n_tokens + TOK - 1) / TOK;
        dim3 grid(groups, 4);
        gemm_all<<<grid, 256, TOK * OUT_DIM * sizeof(float), stream>>>(
            b0, b1, b2, b3, t0, t1, t2, t3, lists, counts, out, n_tokens);
    } else {
        per_token_kernel<<<n_tokens, 256, 0, stream>>>(
            src, ba, la, b0, b1, b2, b3, t0, t1, t2, t3, out);
    }
}

// Round 6
// 152.918 us; speedup vs baseline: 2.3866x; 1.0231x over previous
//
#include <hip/hip_runtime.h>
#include <stdint.h>

// BlockWiseEmbedding via bf16 MFMA, v4 (per-block M-tiles, fused prep+scatter, NT C stores).
// Inputs (setup_inputs dict order, INTERLEAVED):
//   0:src 1:block_assignment 2:local_assignment 3:block0 4:trans0 5:block1 6:trans1
//   7:block2 8:trans2 9:block3 10:trans3
// Pipeline: (1) memset counts (16 B); (2) prep_scatter: WGs 0..239 swizzle trans -> bf16 MFMA
//           B-fragments, WGs 240..303 compact tokens by block (LDS-aggregated atomics);
//           (3) gemm4: flattened indirect grid; per-block tile: S=64/128 -> 32 tokens/WG
//           (acc[2][4]), S=256/512 -> 16 tokens/WG (acc[4]); nontemporal C stores.

#define OUT_DIM 512
#define TOKBITS 14
#define TOKMASK ((1 << TOKBITS) - 1)

typedef __attribute__((ext_vector_type(8))) short short8;   // 8 x bf16 (4 VGPRs)
typedef __attribute__((ext_vector_type(4))) float floatx4;  // MFMA C/D

__device__ __forceinline__ uint16_t f2bf(float f) {
    union { float f; uint32_t u; } x; x.f = f;
    uint32_t u = x.u + 0x7FFF + ((x.u >> 16) & 1);  // RNE
    return (uint16_t)(u >> 16);
}

// ---- (2) Fused: B-fragment pre-swizzle (WGs 0..239) + token scatter (WGs 240..303) ----
// Frag f within block: lane=f&63, rest=f>>6, ks=rest%KS, ntile=rest/KS;
// lane: quad=lane>>4, nl=lane&15 -> B[k=ks*32+quad*8+j][n=ntile*16+nl], j=0..7.
__global__ __launch_bounds__(256) void prep_scatter(
    const float* __restrict__ t0, const float* __restrict__ t1,
    const float* __restrict__ t2, const float* __restrict__ t3,
    uint16_t* __restrict__ bsw,
    const int* __restrict__ src, const int* __restrict__ ba, const int* __restrict__ la,
    int* __restrict__ counts, int* __restrict__ lists, int n_tokens, int stride) {
    const int bx = (int)blockIdx.x;
    const int tid = (int)threadIdx.x;
    if (bx < 240) {
        int gid = bx * 256 + tid;   // 61440 frags total
        const float* tr; int S; int f; uint16_t* dst;
        if (gid < 4096)       { tr = t0; S = 64;  f = gid;         dst = bsw; }
        else if (gid < 12288) { tr = t1; S = 128; f = gid - 4096;  dst = bsw + 64 * 512; }
        else if (gid < 28672) { tr = t2; S = 256; f = gid - 12288; dst = bsw + (64 + 128) * 512; }
        else                  { tr = t3; S = 512; f = gid - 28672; dst = bsw + (64 + 128 + 256) * 512; }
        const int lane = f & 63, rest = f >> 6;
        const int ksteps = S >> 5;
        const int ks = rest & (ksteps - 1), ntile = rest / ksteps;
        const int quad = lane >> 4, nl = lane & 15;
        const int n = ntile * 16 + nl, k0 = ks * 32 + quad * 8;
        short8 v;
#pragma unroll
        for (int j = 0; j < 8; ++j) v[j] = (short)f2bf(tr[(k0 + j) * OUT_DIM + n]);
        *(short8*)(dst + (size_t)f * 8) = v;
    } else {
        __shared__ int lc[4], gbase[4];
        if (tid < 4) lc[tid] = 0;
        __syncthreads();
        const int t = (bx - 240) * 256 + tid;
        int b = 0, pos = 0, packed = 0;
        const bool active = (t < n_tokens);
        if (active) {
            int v = src[t];
            b = ba[v];
            int r = min(max(la[v], 0), 24999);
            packed = t | (r << TOKBITS);
            pos = atomicAdd(&lc[b], 1);
        }
        __syncthreads();
        if (tid < 4) gbase[tid] = atomicAdd(&counts[tid], lc[tid]);  // counts pre-zeroed by memset
        __syncthreads();
        if (active) lists[b * stride + gbase[b] + pos] = packed;
    }
}

// ---- (3) MFMA GEMM v4: MT*16 tokens x 256 out dims per WG, indirect flattened grid ----
template <int S, int MT>
__device__ __forceinline__ void gemm4_body(
    const float* __restrict__ tbl, const uint16_t* __restrict__ bswb,
    const int* __restrict__ list, int n, int g, int nhalf,
    float* __restrict__ out, uint16_t* lds) {
    constexpr int ROWS = MT * 16;
    const int base = g * ROWS;
    const int m = min(ROWS, n - base);
    const int tid = (int)threadIdx.x;
    constexpr int SP = S + 8;              // row stride ≡ 4 dwords mod 32 -> 2-way max (free)
    constexpr int CH = S / 4;              // float4 chunks per row
    constexpr int KS = S / 32;

    // Stage token rows -> LDS bf16.
    for (int i = tid; i < ROWS * CH; i += 256) {
        const int row = i / CH, c = i & (CH - 1);
        float4 v = make_float4(0.f, 0.f, 0.f, 0.f);
        if (row < m) {
            const int r = list[base + row] >> TOKBITS;
            v = ((const float4*)(tbl + (size_t)r * S))[c];
        }
        const uint32_t lo = ((uint32_t)f2bf(v.y) << 16) | f2bf(v.x);
        const uint32_t hi = ((uint32_t)f2bf(v.w) << 16) | f2bf(v.z);
        *(uint2*)(lds + row * SP + c * 4) = make_uint2(lo, hi);
    }
    __syncthreads();

    const int wave = tid >> 6, lane = tid & 63;
    const int quad = lane >> 4, ml = lane & 15;
    const int ntb = nhalf * 16 + wave * 4;  // this wave's first of 4 ntiles

    floatx4 acc[MT][4];
#pragma unroll
    for (int mt = 0; mt < MT; ++mt)
#pragma unroll
        for (int nt = 0; nt < 4; ++nt) acc[mt][nt] = (floatx4)0.f;

    const short8* B = (const short8*)bswb;
#pragma unroll
    for (int ks = 0; ks < KS; ++ks) {
        short8 a[MT];
#pragma unroll
        for (int mt = 0; mt < MT; ++mt)
            a[mt] = *(const short8*)(lds + (mt * 16 + ml) * SP + ks * 32 + quad * 8);
#pragma unroll
        for (int nt = 0; nt < 4; ++nt) {
            const short8 bf = B[(size_t)((ntb + nt) * KS + ks) * 64 + lane];
#pragma unroll
            for (int mt = 0; mt < MT; ++mt)
                acc[mt][nt] = __builtin_amdgcn_mfma_f32_16x16x32_bf16(a[mt], bf, acc[mt][nt], 0, 0, 0);
        }
    }

    // C/D: col = lane&15, row = quad*4 + reg. Nontemporal: C is write-only, keep L2 for B.
#pragma unroll
    for (int mt = 0; mt < MT; ++mt) {
#pragma unroll
        for (int r = 0; r < 4; ++r) {
            const int tokidx = mt * 16 + quad * 4 + r;
            if (tokidx < m) {
                const int t = list[base + tokidx] & TOKMASK;
                float* op = out + (size_t)t * OUT_DIM + nhalf * 256 + wave * 64 + ml;
#pragma unroll
                for (int nt = 0; nt < 4; ++nt)
                    __builtin_nontemporal_store(acc[mt][nt][r], op + nt * 16);
            }
        }
    }
}

__global__ __launch_bounds__(256, 5) void gemm_mfma_v4(
    const float* __restrict__ b0, const float* __restrict__ b1,
    const float* __restrict__ b2, const float* __restrict__ b3,
    const uint16_t* __restrict__ bsw,
    const int* __restrict__ lists, const int* __restrict__ counts,
    float* __restrict__ out, int stride) {
    extern __shared__ uint16_t lds[];       // max 16 * (512+8) * 2 = 16640 B
    const int c0 = counts[0], c1 = counts[1], c2 = counts[2], c3 = counts[3];
    const int g0 = (c0 + 31) >> 5, g1 = (c1 + 31) >> 5;   // MT=2: 32 tokens/WG
    const int g2 = (c2 + 15) >> 4, g3 = (c3 + 15) >> 4;   // MT=1: 16 tokens/WG
    const int flat = (int)blockIdx.x;
    const int nhalf = (int)blockIdx.y;
    if (flat >= g0 + g1 + g2 + g3) return;
    if (flat < g0) {
        gemm4_body<64, 2>(b0, bsw, lists + 0L * stride, c0, flat, nhalf, out, lds);
    } else if (flat < g0 + g1) {
        gemm4_body<128, 2>(b1, bsw + 64 * 512, lists + 1L * stride, c1, flat - g0, nhalf, out, lds);
    } else if (flat < g0 + g1 + g2) {
        gemm4_body<256, 1>(b2, bsw + (64 + 128) * 512, lists + 2L * stride, c2, flat - g0 - g1, nhalf, out, lds);
    } else {
        gemm4_body<512, 1>(b3, bsw + (64 + 128 + 256) * 512, lists + 3L * stride, c3, flat - g0 - g1 - g2, nhalf, out, lds);
    }
}

// ---- Fallback fp32 path (ws too small for bsw) ----
#define TOK 16
__global__ __launch_bounds__(256) void scatter_kernel(
    const int* __restrict__ src, const int* __restrict__ ba, const int* __restrict__ la,
    int* __restrict__ counts, int* __restrict__ lists, int n_tokens, int stride) {
    __shared__ int lc[4], gbase[4];
    const int tid = (int)threadIdx.x;
    if (tid < 4) lc[tid] = 0;
    __syncthreads();
    const int t = blockIdx.x * 256 + tid;
    int b = 0, pos = 0, packed = 0;
    const bool active = (t < n_tokens);
    if (active) {
        int v = src[t];
        b = ba[v];
        int r = min(max(la[v], 0), 24999);
        packed = t | (r << TOKBITS);
        pos = atomicAdd(&lc[b], 1);
    }
    __syncthreads();
    if (tid < 4) gbase[tid] = atomicAdd(&counts[tid], lc[tid]);
    __syncthreads();
    if (active) lists[b * stride + gbase[b] + pos] = packed;
}

template <int S>
__device__ __forceinline__ void gemm_body(const float* __restrict__ tbl,
                                          const float* __restrict__ tr,
                                          const int* __restrict__ list,
                                          const int* __restrict__ counts,
                                          float* __restrict__ out,
                                          float* lvec, int b) {
    const int n = counts[b];
    const int base = (int)blockIdx.x * TOK;
    if (base >= n) return;
    const int m = min(TOK, n - base);
    const int tid = (int)threadIdx.x;
    const int nch = TOK * S / 4;
    for (int i = tid; i < nch; i += 256) {
        const int tok = i / (S / 4), c = i % (S / 4);
        float4 v = make_float4(0.f, 0.f, 0.f, 0.f);
        if (tok < m) {
            const int row = list[base + tok] >> TOKBITS;
            v = ((const float4*)(tbl + (size_t)row * S))[c];
        }
        ((float4*)lvec)[i] = v;
    }
    __syncthreads();
    float acc0[TOK], acc1[TOK];
#pragma unroll
    for (int tok = 0; tok < TOK; ++tok) { acc0[tok] = 0.f; acc1[tok] = 0.f; }
#pragma unroll 2
    for (int k = 0; k < S; k += 4) {
        float w00 = tr[(k + 0) * OUT_DIM + tid], w01 = tr[(k + 0) * OUT_DIM + tid + 256];
        float w10 = tr[(k + 1) * OUT_DIM + tid], w11 = tr[(k + 1) * OUT_DIM + tid + 256];
        float w20 = tr[(k + 2) * OUT_DIM + tid], w21 = tr[(k + 2) * OUT_DIM + tid + 256];
        float w30 = tr[(k + 3) * OUT_DIM + tid], w31 = tr[(k + 3) * OUT_DIM + tid + 256];
#pragma unroll
        for (int tok = 0; tok < TOK; ++tok) {
            float4 tv = *(const float4*)&lvec[tok * S + k];
            acc0[tok] += tv.x * w00 + tv.y * w10 + tv.z * w20 + tv.w * w30;
            acc1[tok] += tv.x * w01 + tv.y * w11 + tv.z * w21 + tv.w * w31;
        }
    }
    for (int tok = 0; tok < m; ++tok) {
        const int t = list[base + tok] & TOKMASK;
        out[(size_t)t * OUT_DIM + tid] = acc0[tok];
        out[(size_t)t * OUT_DIM + tid + 256] = acc1[tok];
    }
}

__global__ __launch_bounds__(256) void gemm_all(
    const float* __restrict__ b0, const float* __restrict__ b1,
    const float* __restrict__ b2, const float* __restrict__ b3,
    const float* __restrict__ t0, const float* __restrict__ t1,
    const float* __restrict__ t2, const float* __restrict__ t3,
    const int* __restrict__ lists, const int* __restrict__ counts,
    float* __restrict__ out, int stride) {
    extern __shared__ float lvec[];
    switch ((int)blockIdx.y) {
        case 0: gemm_body<64 >(b0, t0, lists + 0L * stride, counts, out, lvec, 0); break;
        case 1: gemm_body<128>(b1, t1, lists + 1L * stride, counts, out, lvec, 1); break;
        case 2: gemm_body<256>(b2, t2, lists + 2L * stride, counts, out, lvec, 2); break;
        case 3: gemm_body<512>(b3, t3, lists + 3L * stride, counts, out, lvec, 3); break;
    }
}

// ---- Last-resort fallback: one WG per token ----
__global__ __launch_bounds__(256) void per_token_kernel(
    const int* __restrict__ src, const int* __restrict__ ba, const int* __restrict__ la,
    const float* __restrict__ b0, const float* __restrict__ b1,
    const float* __restrict__ b2, const float* __restrict__ b3,
    const float* __restrict__ t0, const float* __restrict__ t1,
    const float* __restrict__ t2, const float* __restrict__ t3,
    float* __restrict__ out) {
    __shared__ float lvec[OUT_DIM];
    const int t = (int)blockIdx.x, tid = (int)threadIdx.x;
    const int v = src[t];
    const int b = ba[v];
    int r = min(max(la[v], 0), 24999);
    const float* tbl; const float* tr; int S;
    switch (b) {
        case 0: tbl = b0; tr = t0; S = 64;  break;
        case 1: tbl = b1; tr = t1; S = 128; break;
        case 2: tbl = b2; tr = t2; S = 256; break;
        default: tbl = b3; tr = t3; S = 512; break;
    }
    if (tid < S / 4) ((float4*)lvec)[tid] = ((const float4*)(tbl + (size_t)r * S))[tid];
    __syncthreads();
    float acc0 = 0.f, acc1 = 0.f;
    for (int k = 0; k < S; ++k) {
        float x = lvec[k];
        acc0 += x * tr[k * OUT_DIM + tid];
        acc1 += x * tr[k * OUT_DIM + tid + 256];
    }
    out[(size_t)t * OUT_DIM + tid] = acc0;
    out[(size_t)t * OUT_DIM + tid + 256] = acc1;
}

extern "C" void kernel_launch(void* const* d_in, const int* in_sizes, int n_in,
                              void* d_out, int out_size, void* d_ws, size_t ws_size,
                              hipStream_t stream) {
    const int*   src = (const int*)d_in[0];
    const int*   ba  = (const int*)d_in[1];
    const int*   la  = (const int*)d_in[2];
    const float* b0  = (const float*)d_in[3];
    const float* t0  = (const float*)d_in[4];
    const float* b1  = (const float*)d_in[5];
    const float* t1  = (const float*)d_in[6];
    const float* b2  = (const float*)d_in[7];
    const float* t2  = (const float*)d_in[8];
    const float* b3  = (const float*)d_in[9];
    const float* t3  = (const float*)d_in[10];
    float* out = (float*)d_out;

    const int n_tokens = in_sizes[0];                   // 16384
    const size_t off_lists = 16;
    const size_t off_bsw   = off_lists + (size_t)4 * n_tokens * sizeof(int);
    const size_t bsw_bytes = (size_t)(64 + 128 + 256 + 512) * 512 * sizeof(uint16_t);
    const size_t need_full = off_bsw + bsw_bytes;
    const size_t need_fp32 = off_bsw;

    if (d_ws != nullptr && ws_size >= need_full) {
        int* counts   = (int*)d_ws;
        int* lists    = (int*)((char*)d_ws + off_lists);
        uint16_t* bsw = (uint16_t*)((char*)d_ws + off_bsw);
        hipMemsetAsync(d_ws, 0, 16, stream);            // zero counts before fused scatter
        const int scatter_wgs = (n_tokens + 255) / 256; // 64
        prep_scatter<<<240 + scatter_wgs, 256, 0, stream>>>(
            t0, t1, t2, t3, bsw, src, ba, la, counts, lists, n_tokens, n_tokens);
        const int gmax = (n_tokens + 15) / 16 + 3;      // worst-case flattened groups
        dim3 grid(gmax, 2);
        gemm_mfma_v4<<<grid, 256, 16 * (512 + 8) * sizeof(uint16_t), stream>>>(
            b0, b1, b2, b3, bsw, lists, counts, out, n_tokens);
    } else if (d_ws != nullptr && ws_size >= need_fp32) {
        int* counts = (int*)d_ws;
        int* lists  = (int*)((char*)d_ws + off_lists);
        hipMemsetAsync(d_ws, 0, 16, stream);
        scatter_kernel<<<(n_tokens + 255) / 256, 256, 0, stream>>>(
            src, ba, la, counts, lists, n_tokens, n_tokens);
        const int groups = (n_tokens + TOK - 1) / TOK;
        dim3 grid(groups, 4);
        gemm_all<<<grid, 256, TOK * OUT_DIM * sizeof(float), stream>>>(
            b0, b1, b2, b3, t0, t1, t2, t3, lists, counts, out, n_tokens);
    } else {
        per_token_kernel<<<n_tokens, 256, 0, stream>>>(
            src, ba, la, b0, b1, b2, b3, t0, t1, t2, t3, out);
    }
}